// Round 8
// baseline (111.234 us; speedup 1.0000x reference)
//
#include <hip/hip_runtime.h>

// RGate: apply Rx(angle[i]) to every qubit of a 22-qubit statevector.
// Gate on amp-bit k pairs indices at stride 2^k and uses angle[21-k].
//
// Accounting (R3/R5 reproduce to 0.3us): dur_us = ~43us harness fill +
// passA + passB. R5 direct: A(512thr,64KB)=47us @1.06TB/s, occ 37.7% ->
// latency-exposed cold reads, too few waves. This version: BOTH passes at
// 1024 thr (16 waves/block) x 2 blocks/CU = 32 waves/CU (100% cap),
// 8 amps/thread, one barrier each.
//   Pass A: bits 0-12. P1: gates {0,1}(r) {12}(q) {2-7}(shfl). LDS. 
//           P2: gates {8,9,10}(reg) {11}(shfl32). 128B-line stores.
//   Pass B: bits 13-21. P1: gates {13,14,15}(reg) {16,17}(shfl). LDS.
//           P2: gates {18,19,20}(reg) {21}(shfl32). XCD remap kept.

constexpr int NTOT = 1 << 22;   // 2^22 amplitudes

__device__ __forceinline__ void rotg(float& ar, float& ai, float& br, float& bi,
                                     float c, float s) {
    // a' = c*a - i*s*b ; b' = c*b - i*s*a
    float t0 = ar, t1 = ai, t2 = br, t3 = bi;
    ar = fmaf(c, t0,  s * t3);
    ai = fmaf(c, t1, -s * t2);
    br = fmaf(c, t2,  s * t1);
    bi = fmaf(c, t3, -s * t0);
}

// NB butterfly gates for amp bits K0..K0+NB-1; amp bit (K0+b) lives at
// register-index bit (MSH+b). Angles wave-uniform. N = regs per thread.
template<int K0, int NB, int MSH, int N>
__device__ __forceinline__ void gatesM(float (&ar)[N], float (&ai)[N],
                                       const float* __restrict__ ang) {
    #pragma unroll
    for (int b = 0; b < NB; ++b) {
        const int m = 1 << (MSH + b);
        float c, s;
        sincosf(0.5f * ang[21 - (K0 + b)], &s, &c);
        #pragma unroll
        for (int j = 0; j < N; ++j)
            if (!(j & m)) rotg(ar[j], ai[j], ar[j | m], ai[j | m], c, s);
    }
}

// Cross-lane gate: partner = lane ^ XOR. Symmetric update valid on both sides:
// x_r' = c*x_r + s*p_i ; x_i' = c*x_i - s*p_r.
template<int XOR, int N>
__device__ __forceinline__ void shflgate(float (&ar)[N], float (&ai)[N],
                                         float c, float s) {
    #pragma unroll
    for (int j = 0; j < N; ++j) {
        float pr = __shfl_xor(ar[j], XOR, 64);
        float pi = __shfl_xor(ai[j], XOR, 64);
        ar[j] = fmaf(c, ar[j],  s * pi);
        ai[j] = fmaf(c, ai[j], -s * pr);
    }
}

// Pass-A LDS swizzle (float2 elems, bank-pair = idx&15): XOR bits 4-7 into
// 0-3. Both arrangements verified at the 4-lane/bank-pair b64 floor.
__device__ __forceinline__ int slot(int i) { return i ^ ((i >> 4) & 15); }

// ---------------- Pass A: bits 0..12, tile = 8192 contiguous ---------------
// 1024 thr (16 waves, w=t>>6), 8 amps/thread, LDS 8192 float2 = 64 KB.
// Phase 1: i1 = r | l<<2 | w<<8 | q<<12  (reg bits: 0,1=r, 2=q).
//   Loads: per-instr 64 lanes x 16B = 1 KB contiguous.
//   Gates: 0,1 (r); 12 (q); 2-7 (shfl_xor 1..32 = lane bits 0-5).
// ONE __syncthreads. Phase 2: i2 = (l&31) | (w&7)<<5 | j<<8 | (l>>5)<<11
//   | (w>>3)<<12  (reg bits 0-2 = amp bits 8-10).
//   Gates: 8,9,10 (reg); 11 (shfl_xor 32 = lane bit 5).
//   Stores: per-instr two 128 B full-line segments.
__global__ __launch_bounds__(1024) void rgate_A(const float* __restrict__ xr,
                                                const float* __restrict__ xi,
                                                const float* __restrict__ ang,
                                                float* __restrict__ out) {
    __shared__ float2 sv[8192];          // 64 KB
    const int t = threadIdx.x;
    const int l = t & 63, w = t >> 6;
    const int g0 = blockIdx.x << 13;

    const int base1 = (l << 2) | (w << 8);

    float ar[8], ai[8];
    #pragma unroll
    for (int q = 0; q < 2; ++q) {
        const int i = base1 | (q << 12);
        float4 vr = *(const float4*)(xr + g0 + i);
        float4 vi = *(const float4*)(xi + g0 + i);
        ar[4*q+0] = vr.x; ar[4*q+1] = vr.y; ar[4*q+2] = vr.z; ar[4*q+3] = vr.w;
        ai[4*q+0] = vi.x; ai[4*q+1] = vi.y; ai[4*q+2] = vi.z; ai[4*q+3] = vi.w;
    }
    gatesM<0, 2, 0>(ar, ai, ang);        // amp bits 0,1 (reg bits 0,1 = r)
    gatesM<12, 1, 2>(ar, ai, ang);       // amp bit 12   (reg bit 2 = q)

    {   // amp bits 2-7 = lane bits 0-5: six cross-lane gates
        float c, s;
        sincosf(0.5f * ang[21 - 2], &s, &c); shflgate< 1>(ar, ai, c, s);
        sincosf(0.5f * ang[21 - 3], &s, &c); shflgate< 2>(ar, ai, c, s);
        sincosf(0.5f * ang[21 - 4], &s, &c); shflgate< 4>(ar, ai, c, s);
        sincosf(0.5f * ang[21 - 5], &s, &c); shflgate< 8>(ar, ai, c, s);
        sincosf(0.5f * ang[21 - 6], &s, &c); shflgate<16>(ar, ai, c, s);
        sincosf(0.5f * ang[21 - 7], &s, &c); shflgate<32>(ar, ai, c, s);
    }

    #pragma unroll
    for (int q = 0; q < 2; ++q)
        #pragma unroll
        for (int r = 0; r < 4; ++r)
            sv[slot(base1 | (q << 12) | r)] = make_float2(ar[4*q+r], ai[4*q+r]);
    __syncthreads();                     // the single block-level exchange

    const int base2 = (l & 31) | ((w & 7) << 5) | ((l >> 5) << 11)
                    | ((w >> 3) << 12);
    #pragma unroll
    for (int j = 0; j < 8; ++j) {
        float2 v = sv[slot(base2 | (j << 8))];
        ar[j] = v.x; ai[j] = v.y;
    }
    gatesM<8, 3, 0>(ar, ai, ang);        // amp bits 8,9,10 (reg bits 0-2)
    {   // amp bit 11 = lane bit 5
        float c, s;
        sincosf(0.5f * ang[21 - 11], &s, &c);
        shflgate<32>(ar, ai, c, s);
    }

    #pragma unroll
    for (int j = 0; j < 8; ++j) {
        const int i = base2 | (j << 8);
        out[g0 + i]        = ar[j];      // per-instr: 2 x 128B full lines
        out[NTOT + g0 + i] = ai[j];
    }
}

// ---------------- Pass B: bits 13..21 (h stride 8192) ----------------------
// amp = h*8192 + blk*16 + sub ; h in [0,512). Tile = all h x 16 l = 64 KB.
// 1024 thr (16 waves), 8 amps/thread. sub=t&15, l4=(t>>4)&1, l5=(t>>5)&1,
// w=t>>6 in [0,16).
// Phase 1: h = j | l4<<3 | l5<<4 | w<<5  (reg bits 0-2 = h bits 0-2).
//   Gates: 13,14,15 (reg); 16 (shfl 16 = l4); 17 (shfl 32 = l5).
// ONE __syncthreads. Phase 2: h' = (w&15) | l4<<4 | j<<5 | l5<<8.
//   Gates: 18,19,20 (reg j = h bits 5-7); 21 (shfl 32 = l5 = h bit 8).
// LDS sv[h*16+sub]: idx&15 = sub for both arrangements -> b64 floor.
// XCD-contiguous remap kept from the measured-fast build.
__global__ __launch_bounds__(1024) void rgate_B(const float* __restrict__ ang,
                                                float* __restrict__ out) {
    __shared__ float2 sv[8192];          // 64 KB
    const int t   = threadIdx.x;
    const int bid = blockIdx.x;
    const int blk = (bid >> 3) | ((bid & 7) << 6);   // XCD-contiguous remap
    const int sub = t & 15;
    const int l4  = (t >> 4) & 1, l5 = (t >> 5) & 1;
    const int w   = t >> 6;
    const int lbase = (blk << 4) + sub;
    float* outr = out;
    float* outi = out + NTOT;

    float ar[8], ai[8];
    #pragma unroll
    for (int j = 0; j < 8; ++j) {
        const int h = j | (l4 << 3) | (l5 << 4) | (w << 5);
        const int g = (h << 13) + lbase;
        ar[j] = outr[g]; ai[j] = outi[g];
    }
    gatesM<13, 3, 0>(ar, ai, ang);       // amp bits 13,14,15 (reg bits 0-2)
    {   // amp bit 16 = h bit 3 = lane bit 4 ; amp bit 17 = h bit 4 = lane bit 5
        float c, s;
        sincosf(0.5f * ang[21 - 16], &s, &c); shflgate<16>(ar, ai, c, s);
        sincosf(0.5f * ang[21 - 17], &s, &c); shflgate<32>(ar, ai, c, s);
    }

    #pragma unroll
    for (int j = 0; j < 8; ++j) {
        const int h = j | (l4 << 3) | (l5 << 4) | (w << 5);
        sv[(h << 4) | sub] = make_float2(ar[j], ai[j]);
    }
    __syncthreads();                     // the single block-level exchange

    #pragma unroll
    for (int j = 0; j < 8; ++j) {
        const int h = (w & 15) | (l4 << 4) | (j << 5) | (l5 << 8);
        float2 v = sv[(h << 4) | sub];
        ar[j] = v.x; ai[j] = v.y;
    }
    gatesM<18, 3, 0>(ar, ai, ang);       // amp bits 18,19,20 (reg bits 0-2)
    {   // amp bit 21 = h bit 8 = lane bit 5
        float c, s;
        sincosf(0.5f * ang[21 - 21], &s, &c);
        shflgate<32>(ar, ai, c, s);
    }

    #pragma unroll
    for (int j = 0; j < 8; ++j) {
        const int h = (w & 15) | (l4 << 4) | (j << 5) | (l5 << 8);
        const int g = (h << 13) + lbase;
        outr[g] = ar[j]; outi[g] = ai[j];
    }
}

extern "C" void kernel_launch(void* const* d_in, const int* in_sizes, int n_in,
                              void* d_out, int out_size, void* d_ws, size_t ws_size,
                              hipStream_t stream) {
    const float* xr  = (const float*)d_in[0];
    const float* xi  = (const float*)d_in[1];
    const float* ang = (const float*)d_in[2];
    float* out = (float*)d_out;

    // Pass A: bits 0-12, d_in -> d_out (fully overwrites d_out)
    rgate_A<<<512, 1024, 0, stream>>>(xr, xi, ang, out);
    // Pass B: bits 13-21, in-place on d_out
    rgate_B<<<512, 1024, 0, stream>>>(ang, out);
}